// Round 4
// baseline (462.369 us; speedup 1.0000x reference)
//
#include <hip/hip_runtime.h>
#include <stdint.h>

// B=4, S=2048, D_IN=D_MODEL=1024.
// Pipeline (7 launches):
//   memset scales -> absmax(W) -> quantize W^T bf16 ->
//   proj_gemm  (A = fp32 q/k/v converted in-staging; z<2 -> fp8 qp8/kp8,
//               z==2 -> bf16 vp^T)                      [cast3 fused away]
//   qk_fp8     (MX-scaled fp8 MFMA, K=128/instr; epilogue also emits
//               per-(row, bn-tile) partial max / sumexp)
//   ml_reduce  (combine 16 partials -> (m, 1/l) per row)
//   pv_gemm    (A-staging applies exp(logit - m); epilogue scales by 1/l)
//                                                        [softmax fused away]
// All GEMM LDS staging uses the XOR chunk-swizzle (chunk ^= row&7) ->
// zero bank conflicts. Grids bm-fastest for XCD A-stripe L2 sharing.
// fp8 only on the softmax-attenuated path (qp/kp); vp & probs stay bf16.

typedef unsigned short ushort_t;
typedef __attribute__((ext_vector_type(8))) short short8;
typedef __bf16 bf16x8 __attribute__((ext_vector_type(8)));
typedef __attribute__((ext_vector_type(4))) float floatx4;
typedef __attribute__((ext_vector_type(8))) int int8v;

__device__ __forceinline__ ushort_t f2bf(float x) {
  unsigned u = __float_as_uint(x);
  unsigned r = (u + 0x7fffu + ((u >> 16) & 1u)) >> 16;  // RNE
  return (ushort_t)r;
}
__device__ __forceinline__ float bf2f(ushort_t u) {
  return __uint_as_float(((unsigned)u) << 16);
}
__device__ __forceinline__ unsigned char f2fp8(float x) {
  return (unsigned char)(__builtin_amdgcn_cvt_pk_fp8_f32(x, x, 0, false) & 0xff);
}
__device__ __forceinline__ void gl_lds16(const void* g, void* l) {
  __builtin_amdgcn_global_load_lds(
      (const __attribute__((address_space(1))) unsigned int*)g,
      (__attribute__((address_space(3))) unsigned int*)l, 16, 0, 0);
}

// ---------------- proj_gemm ----------------
// M=8192, N=1024, K=1024 per z. A fp32 (q/k/v), B = Wt bf16 (W^T, N-major).
// Grid (64 bm, 8 bn, 3 z).
__global__ __launch_bounds__(256, 2) void proj_gemm(
    const float* __restrict__ Aq, const float* __restrict__ Ak,
    const float* __restrict__ Av, const ushort_t* __restrict__ Bt,
    unsigned char* __restrict__ qp8, unsigned char* __restrict__ kp8,
    ushort_t* __restrict__ vpT, const float* __restrict__ bq,
    const float* __restrict__ bk, const float* __restrict__ bv) {
  __shared__ __attribute__((aligned(16))) ushort_t sA[128 * 64];
  __shared__ __attribute__((aligned(16))) ushort_t sB[128 * 64];
  const int t = threadIdx.x, lane = t & 63, wave = t >> 6;
  const int bm = blockIdx.x, bn = blockIdx.y, bz = blockIdx.z;
  const float* A = bz == 0 ? Aq : (bz == 1 ? Ak : Av);
  const float* bias = bz == 0 ? bq : (bz == 1 ? bk : bv);
  const ushort_t* Bb = Bt + (long)bz * 1048576L;
  const long a_row0 = (long)bm * 128, b_row0 = (long)bn * 128;

  // Staging geometry: 32 rows x 8 chunks(16B dst) per issue, 4 issues.
  // LDS[row][c] holds global chunk g = c ^ (row&7)  (involutive swizzle).
  const int crow = t >> 3, c = t & 7, g = c ^ (crow & 7);
  const float* gA = A + (a_row0 + crow) * 1024L + g * 8;      // 8 fp32 = 32B
  const ushort_t* gB = Bb + (b_row0 + crow) * 1024L + g * 8;  // 8 bf16 = 16B
  ushort_t* lB = sB + wave * 512;
  const int ldsA = crow * 64 + c * 8;  // elements; + i*2048 per issue

  floatx4 acc[4][4];
#pragma unroll
  for (int i = 0; i < 4; ++i)
#pragma unroll
    for (int j = 0; j < 4; ++j) acc[i][j] = {0.f, 0.f, 0.f, 0.f};

  const int wm = (wave & 1) * 64, wn = (wave >> 1) * 64;
  const int fr = lane & 15, fg = lane >> 4;
  int offA[2][4], offB[2][4];
#pragma unroll
  for (int s = 0; s < 2; ++s)
#pragma unroll
    for (int i = 0; i < 4; ++i) {
      int rowA = wm + i * 16 + fr, rowB = wn + i * 16 + fr;
      int cg = s * 4 + fg;
      offA[s][i] = rowA * 64 + ((cg ^ (rowA & 7)) * 8);
      offB[s][i] = rowB * 64 + ((cg ^ (rowB & 7)) * 8);
    }

  for (int k0 = 0; k0 < 1024; k0 += 64) {
#pragma unroll
    for (int i = 0; i < 4; ++i)
      gl_lds16(gB + (long)i * 32 * 1024, lB + i * 2048);
    gB += 64;
#pragma unroll
    for (int i = 0; i < 4; ++i) {
      const float* ga = gA + (long)i * 32 * 1024;
      float4 f0 = *(const float4*)ga;
      float4 f1 = *(const float4*)(ga + 4);
      short8 pk;
      pk[0] = (short)f2bf(f0.x); pk[1] = (short)f2bf(f0.y);
      pk[2] = (short)f2bf(f0.z); pk[3] = (short)f2bf(f0.w);
      pk[4] = (short)f2bf(f1.x); pk[5] = (short)f2bf(f1.y);
      pk[6] = (short)f2bf(f1.z); pk[7] = (short)f2bf(f1.w);
      *(short8*)&sA[i * 2048 + ldsA] = pk;
    }
    gA += 64;
    __syncthreads();

#pragma unroll
    for (int s = 0; s < 2; ++s) {
      bf16x8 af[4], bfr[4];
#pragma unroll
      for (int i = 0; i < 4; ++i) {
        af[i] = *(const bf16x8*)&sA[offA[s][i]];
        bfr[i] = *(const bf16x8*)&sB[offB[s][i]];
      }
#pragma unroll
      for (int mi = 0; mi < 4; ++mi)
#pragma unroll
        for (int ni = 0; ni < 4; ++ni)
          acc[mi][ni] = __builtin_amdgcn_mfma_f32_16x16x32_bf16(
              af[mi], bfr[ni], acc[mi][ni], 0, 0, 0);
    }
    __syncthreads();
  }

  // C/D layout: row=(lane>>4)*4+reg, col=lane&15  [m89/m91]
  const int r0 = fg * 4, cc = fr;
  unsigned char* C8 = bz == 0 ? qp8 : kp8;
#pragma unroll
  for (int mi = 0; mi < 4; ++mi) {
#pragma unroll
    for (int ni = 0; ni < 4; ++ni) {
      long gm0 = a_row0 + wm + mi * 16 + r0;
      long gn = b_row0 + wn + ni * 16 + cc;
      float vv[4];
#pragma unroll
      for (int r = 0; r < 4; ++r) vv[r] = acc[mi][ni][r] + bias[gn];
      if (bz == 2) {
        long b = gm0 >> 11, s = gm0 & 2047;
        ushort4 u4;
        u4.x = f2bf(vv[0]); u4.y = f2bf(vv[1]);
        u4.z = f2bf(vv[2]); u4.w = f2bf(vv[3]);
        *(ushort4*)&vpT[b * (2048L * 1024L) + gn * 2048L + s] = u4;
      } else {
#pragma unroll
        for (int r = 0; r < 4; ++r) C8[(gm0 + r) * 1024 + gn] = f2fp8(vv[r]);
      }
    }
  }
}

// ---------------- qk_fp8 ----------------
// logits = qp.kp^T * (1/32), MX-scaled fp8 (scale=2^0=E8M0 127).
// Also emits per-(row, bn) partial max & sumexp. Grid (16 bm, 16 bn, 4 bz).
__global__ __launch_bounds__(256, 2) void qk_fp8(
    const unsigned char* __restrict__ Q8, const unsigned char* __restrict__ K8,
    ushort_t* __restrict__ P, float* __restrict__ Mp, float* __restrict__ Lp) {
  __shared__ __attribute__((aligned(16))) unsigned char sA[128 * 128];
  __shared__ __attribute__((aligned(16))) unsigned char sB[128 * 128];
  __shared__ float redM[2][128];
  __shared__ float redS[2][128];
  const int t = threadIdx.x, lane = t & 63, wave = t >> 6;
  const int bm = blockIdx.x, bn = blockIdx.y, bz = blockIdx.z;

  const unsigned char* Ab = Q8 + (long)bz * 2097152L + (long)bm * 128 * 1024;
  const unsigned char* Bb = K8 + (long)bz * 2097152L + (long)bn * 128 * 1024;

  const int crow = t >> 3;
  const int schunk = (t & 7) ^ (crow & 7);
  const unsigned char* gA = Ab + crow * 1024 + schunk * 16;
  const unsigned char* gB = Bb + crow * 1024 + schunk * 16;
  unsigned char* lA = sA + wave * 1024;
  unsigned char* lB = sB + wave * 1024;

  floatx4 acc[4][4];
#pragma unroll
  for (int i = 0; i < 4; ++i)
#pragma unroll
    for (int j = 0; j < 4; ++j) acc[i][j] = {0.f, 0.f, 0.f, 0.f};

  const int wm = (wave & 1) * 64, wn = (wave >> 1) * 64;
  const int fr = lane & 15, fg = lane >> 4;

  int offA[4][2], offB[4][2];
#pragma unroll
  for (int i = 0; i < 4; ++i) {
    int rA = wm + i * 16 + fr, rB = wn + i * 16 + fr;
    offA[i][0] = rA * 128 + (((2 * fg) ^ (rA & 7)) * 16);
    offA[i][1] = rA * 128 + (((2 * fg + 1) ^ (rA & 7)) * 16);
    offB[i][0] = rB * 128 + (((2 * fg) ^ (rB & 7)) * 16);
    offB[i][1] = rB * 128 + (((2 * fg + 1) ^ (rB & 7)) * 16);
  }

  for (int k0 = 0; k0 < 1024; k0 += 128) {
#pragma unroll
    for (int i = 0; i < 4; ++i) {
      gl_lds16(gA + (long)i * 32 * 1024, lA + i * 4096);
      gl_lds16(gB + (long)i * 32 * 1024, lB + i * 4096);
    }
    gA += 128;
    gB += 128;
    __syncthreads();

    int8v af[4], bfr[4];
#pragma unroll
    for (int i = 0; i < 4; ++i) {
      int4 lo = *(const int4*)&sA[offA[i][0]];
      int4 hi = *(const int4*)&sA[offA[i][1]];
      af[i][0] = lo.x; af[i][1] = lo.y; af[i][2] = lo.z; af[i][3] = lo.w;
      af[i][4] = hi.x; af[i][5] = hi.y; af[i][6] = hi.z; af[i][7] = hi.w;
      int4 lo2 = *(const int4*)&sB[offB[i][0]];
      int4 hi2 = *(const int4*)&sB[offB[i][1]];
      bfr[i][0] = lo2.x; bfr[i][1] = lo2.y; bfr[i][2] = lo2.z; bfr[i][3] = lo2.w;
      bfr[i][4] = hi2.x; bfr[i][5] = hi2.y; bfr[i][6] = hi2.z; bfr[i][7] = hi2.w;
    }
#pragma unroll
    for (int mi = 0; mi < 4; ++mi)
#pragma unroll
      for (int ni = 0; ni < 4; ++ni)
        acc[mi][ni] = __builtin_amdgcn_mfma_scale_f32_16x16x128_f8f6f4(
            af[mi], bfr[ni], acc[mi][ni], 0, 0, 0, 127, 0, 127);
    __syncthreads();
  }

  const float alpha = 0.03125f;
  const int r0 = fg * 4, cc = fr;

  // --- partial row-max over this block's 128 cols (scaled) ---
  float mrow[4][4];
#pragma unroll
  for (int mi = 0; mi < 4; ++mi)
#pragma unroll
    for (int r = 0; r < 4; ++r) {
      float m = acc[mi][0][r];
#pragma unroll
      for (int ni = 1; ni < 4; ++ni) m = fmaxf(m, acc[mi][ni][r]);
      m = fmaxf(m, __shfl_xor(m, 1));
      m = fmaxf(m, __shfl_xor(m, 2));
      m = fmaxf(m, __shfl_xor(m, 4));
      m = fmaxf(m, __shfl_xor(m, 8));
      if (cc == 0) redM[wave >> 1][wm + mi * 16 + fg * 4 + r] = m * alpha;
    }
  __syncthreads();
#pragma unroll
  for (int mi = 0; mi < 4; ++mi)
#pragma unroll
    for (int r = 0; r < 4; ++r) {
      int row = wm + mi * 16 + fg * 4 + r;
      mrow[mi][r] = fmaxf(redM[0][row], redM[1][row]);
    }
  // --- partial sumexp with combined per-block max ---
#pragma unroll
  for (int mi = 0; mi < 4; ++mi)
#pragma unroll
    for (int r = 0; r < 4; ++r) {
      float s = 0.f;
#pragma unroll
      for (int ni = 0; ni < 4; ++ni)
        s += __expf(acc[mi][ni][r] * alpha - mrow[mi][r]);
      s += __shfl_xor(s, 1);
      s += __shfl_xor(s, 2);
      s += __shfl_xor(s, 4);
      s += __shfl_xor(s, 8);
      if (cc == 0) redS[wave >> 1][wm + mi * 16 + fg * 4 + r] = s;
    }
  __syncthreads();
  if ((wave >> 1) == 0 && cc == 0) {
#pragma unroll
    for (int mi = 0; mi < 4; ++mi)
#pragma unroll
      for (int r = 0; r < 4; ++r) {
        int row = wm + mi * 16 + fg * 4 + r;
        long gr = (long)bz * 2048 + (long)bm * 128 + row;
        Mp[gr * 16 + bn] = fmaxf(redM[0][row], redM[1][row]);
        Lp[gr * 16 + bn] = redS[0][row] + redS[1][row];
      }
  }
  // --- raw scaled logits to P (bf16) ---
#pragma unroll
  for (int mi = 0; mi < 4; ++mi)
#pragma unroll
    for (int ni = 0; ni < 4; ++ni)
#pragma unroll
      for (int r = 0; r < 4; ++r) {
        long gm = (long)bm * 128 + wm + mi * 16 + r0 + r;
        long gn = (long)bn * 128 + wn + ni * 16 + cc;
        P[(long)bz * 4194304L + gm * 2048 + gn] = f2bf(acc[mi][ni][r] * alpha);
      }
}

// ---------------- ml_reduce ----------------
__global__ __launch_bounds__(256) void ml_reduce(const float* __restrict__ Mp,
                                                 const float* __restrict__ Lp,
                                                 float2* __restrict__ ML) {
  int row = blockIdx.x * 256 + threadIdx.x;  // 8192 rows
  const float* mp = Mp + (long)row * 16;
  const float* lp = Lp + (long)row * 16;
  float m = mp[0];
#pragma unroll
  for (int j = 1; j < 16; ++j) m = fmaxf(m, mp[j]);
  float l = 0.f;
#pragma unroll
  for (int j = 0; j < 16; ++j) l += lp[j] * __expf(mp[j] - m);
  ML[row] = make_float2(m, 1.0f / l);
}

// ---------------- pv_gemm ----------------
// out = softmax(P) x vpT^T. M=2048, N=1024, K=2048 per batch.
// A-staging: p = exp(logit - m) (bf16); epilogue scales rows by 1/l.
// Grid (16 bm, 8 bn, 4 bz).
__global__ __launch_bounds__(256, 2) void pv_gemm(
    const ushort_t* __restrict__ P, const ushort_t* __restrict__ vpT,
    const float2* __restrict__ ML, float* __restrict__ out) {
  __shared__ __attribute__((aligned(16))) ushort_t sA[128 * 64];
  __shared__ __attribute__((aligned(16))) ushort_t sB[128 * 64];
  const int t = threadIdx.x, lane = t & 63, wave = t >> 6;
  const int bm = blockIdx.x, bn = blockIdx.y, bz = blockIdx.z;
  const ushort_t* Ab = P + (long)bz * 4194304L;
  const ushort_t* Bb = vpT + (long)bz * 2097152L;
  const long a_row0 = (long)bm * 128, b_row0 = (long)bn * 128;

  const int crow = t >> 3, c = t & 7, g = c ^ (crow & 7);
  const ushort_t* gA0 = Ab + (a_row0 + crow) * 2048L + g * 8;
  const ushort_t* gB = Bb + (b_row0 + crow) * 2048L + g * 8;
  ushort_t* lB = sB + wave * 512;
  const int ldsA = crow * 64 + c * 8;

  // Row stats for this thread's 4 staging rows (fixed across K)
  float mrow_s[4];
#pragma unroll
  for (int i = 0; i < 4; ++i)
    mrow_s[i] = ML[(long)bz * 2048 + a_row0 + i * 32 + crow].x;

  floatx4 acc[4][4];
#pragma unroll
  for (int i = 0; i < 4; ++i)
#pragma unroll
    for (int j = 0; j < 4; ++j) acc[i][j] = {0.f, 0.f, 0.f, 0.f};

  const int wm = (wave & 1) * 64, wn = (wave >> 1) * 64;
  const int fr = lane & 15, fg = lane >> 4;
  int offA[2][4], offB[2][4];
#pragma unroll
  for (int s = 0; s < 2; ++s)
#pragma unroll
    for (int i = 0; i < 4; ++i) {
      int rowA = wm + i * 16 + fr, rowB = wn + i * 16 + fr;
      int cg = s * 4 + fg;
      offA[s][i] = rowA * 64 + ((cg ^ (rowA & 7)) * 8);
      offB[s][i] = rowB * 64 + ((cg ^ (rowB & 7)) * 8);
    }

  for (int k0 = 0; k0 < 2048; k0 += 64) {
#pragma unroll
    for (int i = 0; i < 4; ++i)
      gl_lds16(gB + (long)i * 32 * 2048, lB + i * 2048);
    gB += 64;
#pragma unroll
    for (int i = 0; i < 4; ++i) {
      short8 raw = *(const short8*)(gA0 + (long)i * 32 * 2048 + k0);
      short8 pk;
#pragma unroll
      for (int j = 0; j < 8; ++j) {
        float x = bf2f((ushort_t)raw[j]);
        pk[j] = (short)f2bf(__expf(x - mrow_s[i]));
      }
      *(short8*)&sA[i * 2048 + ldsA] = pk;
    }
    __syncthreads();

#pragma unroll
    for (int s = 0; s < 2; ++s) {
      bf16x8 af[4], bfr[4];
#pragma unroll
      for (int i = 0; i < 4; ++i) {
        af[i] = *(const bf16x8*)&sA[offA[s][i]];
        bfr[i] = *(const bf16x8*)&sB[offB[s][i]];
      }
#pragma unroll
      for (int mi = 0; mi < 4; ++mi)
#pragma unroll
        for (int ni = 0; ni < 4; ++ni)
          acc[mi][ni] = __builtin_amdgcn_mfma_f32_16x16x32_bf16(
              af[mi], bfr[ni], acc[mi][ni], 0, 0, 0);
    }
    __syncthreads();
  }

  const int r0 = fg * 4, cc = fr;
#pragma unroll
  for (int mi = 0; mi < 4; ++mi) {
    long gm0 = a_row0 + wm + mi * 16 + r0;
    float il[4];
#pragma unroll
    for (int r = 0; r < 4; ++r) il[r] = ML[(long)bz * 2048 + gm0 + r].y;
#pragma unroll
    for (int ni = 0; ni < 4; ++ni) {
      long gn = b_row0 + wn + ni * 16 + cc;
#pragma unroll
      for (int r = 0; r < 4; ++r)
        out[(long)bz * 2097152L + (gm0 + r) * 1024 + gn] =
            acc[mi][ni][r] * il[r];
    }
  }
}

// ---------------- small prep kernels ----------------
__global__ __launch_bounds__(256) void absmax_k(
    const float* __restrict__ W0, const float* __restrict__ W1,
    const float* __restrict__ W2, unsigned* __restrict__ outv) {
  const float* W = blockIdx.z == 0 ? W0 : (blockIdx.z == 1 ? W1 : W2);
  float m = 0.f;
  const long n = 1024L * 1024L;
  for (long i = (long)blockIdx.x * blockDim.x + threadIdx.x; i < n;
       i += (long)gridDim.x * blockDim.x)
    m = fmaxf(m, fabsf(W[i]));
  for (int off = 32; off; off >>= 1) m = fmaxf(m, __shfl_xor(m, off));
  __shared__ float red[4];
  int lane = threadIdx.x & 63, wave = threadIdx.x >> 6;
  if (lane == 0) red[wave] = m;
  __syncthreads();
  if (threadIdx.x == 0) {
    m = fmaxf(fmaxf(red[0], red[1]), fmaxf(red[2], red[3]));
    atomicMax(&outv[blockIdx.z], __float_as_uint(m));  // positive: uint order
  }
}

__global__ __launch_bounds__(256) void quant_w_k(
    const float* __restrict__ W0, const float* __restrict__ W1,
    const float* __restrict__ W2, const unsigned* __restrict__ scales,
    ushort_t* __restrict__ Wt) {
  const int z = blockIdx.z;
  const float* W = z == 0 ? W0 : (z == 1 ? W1 : W2);
  const float s = __uint_as_float(scales[z]) * (1.0f / 128.0f);
  __shared__ float tile[32][33];
  const int tx = threadIdx.x & 31, ty = threadIdx.x >> 5;
  const int k0 = blockIdx.y * 32, n0 = blockIdx.x * 32;
#pragma unroll
  for (int i = 0; i < 4; ++i)
    tile[ty + i * 8][tx] = W[(long)(k0 + ty + i * 8) * 1024 + n0 + tx];
  __syncthreads();
  ushort_t* wt = Wt + (long)z * 1024 * 1024;
#pragma unroll
  for (int i = 0; i < 4; ++i) {
    float w = tile[tx][ty + i * 8];
    float qv = rintf(w / s) * s;  // rintf = RNE = jnp.round
    wt[(long)(n0 + ty + i * 8) * 1024 + k0 + tx] = f2bf(qv);
  }
}

extern "C" void kernel_launch(void* const* d_in, const int* in_sizes, int n_in,
                              void* d_out, int out_size, void* d_ws,
                              size_t ws_size, hipStream_t stream) {
  const float* q = (const float*)d_in[0];
  const float* k = (const float*)d_in[1];
  const float* v = (const float*)d_in[2];
  const float* Wq = (const float*)d_in[3];
  const float* bq = (const float*)d_in[4];
  const float* Wk = (const float*)d_in[5];
  const float* bk = (const float*)d_in[6];
  const float* Wv = (const float*)d_in[7];
  const float* bv = (const float*)d_in[8];
  float* out = (float*)d_out;
  char* ws = (char*)d_ws;

  // Workspace layout (bytes), total = 106,955,008 (fits the known-good size):
  //   scales @0 (256)
  //   Wt     @256 .. 6,291,712 (6 MB; dead after proj, then overlaid by:)
  //     Mp @256 (512 KB), Lp @524,544 (512 KB), ML @1,048,832 (64 KB)
  //   qp8 @6,291,712  (8 MB)
  //   kp8 @14,680,320 (8 MB)
  //   vpT @23,068,928 (16 MB)  [4][1024][2048] bf16
  //   P   @39,846,144 (64 MB)  [4][2048][2048] bf16 raw scaled logits
  unsigned* scales = (unsigned*)ws;
  ushort_t* Wt = (ushort_t*)(ws + 256);
  float* Mp = (float*)(ws + 256);
  float* Lp = (float*)(ws + 524544);
  float2* ML = (float2*)(ws + 1048832);
  unsigned char* qp8 = (unsigned char*)(ws + 6291712);
  unsigned char* kp8 = (unsigned char*)(ws + 14680320);
  ushort_t* vpT = (ushort_t*)(ws + 23068928);
  ushort_t* P = (ushort_t*)(ws + 39846144);

  hipMemsetAsync(scales, 0, 64, stream);
  absmax_k<<<dim3(64, 1, 3), 256, 0, stream>>>(Wq, Wk, Wv, scales);
  quant_w_k<<<dim3(32, 32, 3), 256, 0, stream>>>(Wq, Wk, Wv, scales, Wt);

  proj_gemm<<<dim3(64, 8, 3), 256, 0, stream>>>(q, k, v, Wt, qp8, kp8, vpT, bq,
                                                bk, bv);
  qk_fp8<<<dim3(16, 16, 4), 256, 0, stream>>>(qp8, kp8, P, Mp, Lp);
  ml_reduce<<<dim3(32), 256, 0, stream>>>(Mp, Lp, ML);
  pv_gemm<<<dim3(16, 8, 4), 256, 0, stream>>>(P, vpT, ML, out);
}

// Round 5
// 316.349 us; speedup vs baseline: 1.4616x; 1.4616x over previous
//
#include <hip/hip_runtime.h>
#include <stdint.h>

// B=4, S=2048, D_IN=D_MODEL=1024.
// Pipeline (7 launches):
//   memset scales -> absmax(W) -> quantize W^T bf16 ->
//   proj_gemm (A staged as RAW fp32 via global_load_lds; fp32->bf16 happens on
//              the LDS->VGPR fragment load with packed cvt — staging stays
//              fully async, unlike the round-4 VGPR-round-trip regression;
//              z<2 -> fp8 qp8/kp8, z==2 -> bf16 vp^T)
//   qk_fp8    (MX-scaled fp8 MFMA, K=128/instr, raw scaled logits -> P bf16)
//   softmax_k (row softmax in place)
//   pv_gemm   (bf16 MFMA, gl_lds staging, fp32 out)
// XOR chunk-swizzle everywhere (A fp32: chunk ^= row&15 over 16 chunks;
// bf16: chunk ^= row&7 over 8) -> conflict-free ds_read_b128.
// Grids bm-fastest for XCD A-stripe L2 sharing.

typedef unsigned short ushort_t;
typedef __attribute__((ext_vector_type(8))) short short8;
typedef __bf16 bf16x8 __attribute__((ext_vector_type(8)));
typedef __bf16 bf16x2 __attribute__((ext_vector_type(2)));
typedef __attribute__((ext_vector_type(4))) float floatx4;
typedef __attribute__((ext_vector_type(8))) int int8v;

__device__ __forceinline__ ushort_t f2bf(float x) {
  unsigned u = __float_as_uint(x);
  unsigned r = (u + 0x7fffu + ((u >> 16) & 1u)) >> 16;  // RNE
  return (ushort_t)r;
}
__device__ __forceinline__ float bf2f(ushort_t u) {
  return __uint_as_float(((unsigned)u) << 16);
}
__device__ __forceinline__ unsigned char f2fp8(float x) {
  return (unsigned char)(__builtin_amdgcn_cvt_pk_fp8_f32(x, x, 0, false) & 0xff);
}
__device__ __forceinline__ void gl_lds16(const void* g, void* l) {
  __builtin_amdgcn_global_load_lds(
      (const __attribute__((address_space(1))) unsigned int*)g,
      (__attribute__((address_space(3))) unsigned int*)l, 16, 0, 0);
}

// 8 fp32 -> bf16x8 (RNE), packed cvt when available.
__device__ __forceinline__ bf16x8 cvt8(float4 f0, float4 f1) {
#if __has_builtin(__builtin_amdgcn_cvt_pk_bf16_f32)
  bf16x2 p0 = __builtin_amdgcn_cvt_pk_bf16_f32(f0.x, f0.y);
  bf16x2 p1 = __builtin_amdgcn_cvt_pk_bf16_f32(f0.z, f0.w);
  bf16x2 p2 = __builtin_amdgcn_cvt_pk_bf16_f32(f1.x, f1.y);
  bf16x2 p3 = __builtin_amdgcn_cvt_pk_bf16_f32(f1.z, f1.w);
  bf16x8 r;
  r[0] = p0[0]; r[1] = p0[1]; r[2] = p1[0]; r[3] = p1[1];
  r[4] = p2[0]; r[5] = p2[1]; r[6] = p3[0]; r[7] = p3[1];
  return r;
#else
  short8 pk;
  pk[0] = (short)f2bf(f0.x); pk[1] = (short)f2bf(f0.y);
  pk[2] = (short)f2bf(f0.z); pk[3] = (short)f2bf(f0.w);
  pk[4] = (short)f2bf(f1.x); pk[5] = (short)f2bf(f1.y);
  pk[6] = (short)f2bf(f1.z); pk[7] = (short)f2bf(f1.w);
  return *(bf16x8*)&pk;
#endif
}

// ---------------- proj_gemm ----------------
// M=8192, N=1024, K=1024 per z. A fp32 (q/k/v) staged raw; B = Wt bf16.
// Grid (64 bm, 8 bn, 3 z). LDS: A 32 KB fp32 + B 16 KB bf16 = 48 KB.
__global__ __launch_bounds__(256, 2) void proj_gemm(
    const float* __restrict__ Aq, const float* __restrict__ Ak,
    const float* __restrict__ Av, const ushort_t* __restrict__ Bt,
    unsigned char* __restrict__ qp8, unsigned char* __restrict__ kp8,
    ushort_t* __restrict__ vpT, const float* __restrict__ bq,
    const float* __restrict__ bk, const float* __restrict__ bv) {
  __shared__ __attribute__((aligned(16))) float sAf[128 * 64];
  __shared__ __attribute__((aligned(16))) ushort_t sB[128 * 64];
  const int t = threadIdx.x, lane = t & 63, wave = t >> 6;
  const int bm = blockIdx.x, bn = blockIdx.y, bz = blockIdx.z;
  const float* A = bz == 0 ? Aq : (bz == 1 ? Ak : Av);
  const float* bias = bz == 0 ? bq : (bz == 1 ? bk : bv);
  const ushort_t* Bb = Bt + (long)bz * 1048576L;
  const long a_row0 = (long)bm * 128, b_row0 = (long)bn * 128;

  // A staging: row = 64 fp32 = 16 chunks(16B). 16 rows/issue, 8 issues.
  // LDS[row][c] holds global chunk c ^ (row&15).
  const int crowA = t >> 4, cA = t & 15, gAc = cA ^ (crowA & 15);
  const float* gA = A + (a_row0 + crowA) * 1024L + gAc * 4;
  // B staging: row = 64 bf16 = 8 chunks(16B). 32 rows/issue, 4 issues.
  const int crowB = t >> 3, cB = t & 7, gBc = cB ^ (crowB & 7);
  const ushort_t* gB = Bb + (b_row0 + crowB) * 1024L + gBc * 8;
  float* lA = sAf + wave * 256;   // + i*1024 per issue; HW adds lane*16B
  ushort_t* lB = sB + wave * 512; // + i*2048 per issue

  floatx4 acc[4][4];
#pragma unroll
  for (int i = 0; i < 4; ++i)
#pragma unroll
    for (int j = 0; j < 4; ++j) acc[i][j] = {0.f, 0.f, 0.f, 0.f};

  const int wm = (wave & 1) * 64, wn = (wave >> 1) * 64;
  const int fr = lane & 15, fg = lane >> 4;
  // A frag offsets (fp32 elements): two 16B chunks per frag per s-step.
  int offA0[2][4], offA1[2][4], offB[2][4];
#pragma unroll
  for (int s = 0; s < 2; ++s)
#pragma unroll
    for (int i = 0; i < 4; ++i) {
      int rowA = wm + i * 16 + fr;
      int rowB = wn + i * 16 + fr;
      int cg = s * 8 + fg * 2;  // 16B-chunk index in fp32 row (0..15)
      offA0[s][i] = rowA * 64 + ((cg ^ (rowA & 15)) * 4);
      offA1[s][i] = rowA * 64 + (((cg + 1) ^ (rowA & 15)) * 4);
      int cgb = s * 4 + fg;  // 16B-chunk index in bf16 row (0..7)
      offB[s][i] = rowB * 64 + ((cgb ^ (rowB & 7)) * 8);
    }

  for (int k0 = 0; k0 < 1024; k0 += 64) {
#pragma unroll
    for (int i = 0; i < 8; ++i)
      gl_lds16(gA + (long)i * 16 * 1024, lA + i * 1024);
    gA += 64;
#pragma unroll
    for (int i = 0; i < 4; ++i)
      gl_lds16(gB + (long)i * 32 * 1024, lB + i * 2048);
    gB += 64;
    __syncthreads();  // staging complete (async DMA drained)

#pragma unroll
    for (int s = 0; s < 2; ++s) {
      bf16x8 af[4], bfr[4];
#pragma unroll
      for (int i = 0; i < 4; ++i) {
        float4 f0 = *(const float4*)&sAf[offA0[s][i]];
        float4 f1 = *(const float4*)&sAf[offA1[s][i]];
        af[i] = cvt8(f0, f1);
        bfr[i] = *(const bf16x8*)&sB[offB[s][i]];
      }
#pragma unroll
      for (int mi = 0; mi < 4; ++mi)
#pragma unroll
        for (int ni = 0; ni < 4; ++ni)
          acc[mi][ni] = __builtin_amdgcn_mfma_f32_16x16x32_bf16(
              af[mi], bfr[ni], acc[mi][ni], 0, 0, 0);
    }
    __syncthreads();
  }

  // C/D layout: row=(lane>>4)*4+reg, col=lane&15  [m89/m91]
  const int r0 = fg * 4, cc = fr;
  unsigned char* C8 = bz == 0 ? qp8 : kp8;
#pragma unroll
  for (int mi = 0; mi < 4; ++mi) {
#pragma unroll
    for (int ni = 0; ni < 4; ++ni) {
      long gm0 = a_row0 + wm + mi * 16 + r0;
      long gn = b_row0 + wn + ni * 16 + cc;
      float vv[4];
#pragma unroll
      for (int r = 0; r < 4; ++r) vv[r] = acc[mi][ni][r] + bias[gn];
      if (bz == 2) {
        long b = gm0 >> 11, s = gm0 & 2047;
        ushort4 u4;
        u4.x = f2bf(vv[0]); u4.y = f2bf(vv[1]);
        u4.z = f2bf(vv[2]); u4.w = f2bf(vv[3]);
        *(ushort4*)&vpT[b * (2048L * 1024L) + gn * 2048L + s] = u4;
      } else {
#pragma unroll
        for (int r = 0; r < 4; ++r) C8[(gm0 + r) * 1024 + gn] = f2fp8(vv[r]);
      }
    }
  }
}

// ---------------- qk_fp8 ----------------
// logits = qp.kp^T * (1/32), MX-scaled fp8 (scale=2^0=E8M0 127).
// Grid (16 bm, 16 bn, 4 bz).
__global__ __launch_bounds__(256, 2) void qk_fp8(
    const unsigned char* __restrict__ Q8, const unsigned char* __restrict__ K8,
    ushort_t* __restrict__ P) {
  __shared__ __attribute__((aligned(16))) unsigned char sA[128 * 128];
  __shared__ __attribute__((aligned(16))) unsigned char sB[128 * 128];
  const int t = threadIdx.x, lane = t & 63, wave = t >> 6;
  const int bm = blockIdx.x, bn = blockIdx.y, bz = blockIdx.z;

  const unsigned char* Ab = Q8 + (long)bz * 2097152L + (long)bm * 128 * 1024;
  const unsigned char* Bb = K8 + (long)bz * 2097152L + (long)bn * 128 * 1024;

  const int crow = t >> 3;
  const int schunk = (t & 7) ^ (crow & 7);
  const unsigned char* gA = Ab + crow * 1024 + schunk * 16;
  const unsigned char* gB = Bb + crow * 1024 + schunk * 16;
  unsigned char* lA = sA + wave * 1024;
  unsigned char* lB = sB + wave * 1024;

  floatx4 acc[4][4];
#pragma unroll
  for (int i = 0; i < 4; ++i)
#pragma unroll
    for (int j = 0; j < 4; ++j) acc[i][j] = {0.f, 0.f, 0.f, 0.f};

  const int wm = (wave & 1) * 64, wn = (wave >> 1) * 64;
  const int fr = lane & 15, fg = lane >> 4;

  int offA[4][2], offB[4][2];
#pragma unroll
  for (int i = 0; i < 4; ++i) {
    int rA = wm + i * 16 + fr, rB = wn + i * 16 + fr;
    offA[i][0] = rA * 128 + (((2 * fg) ^ (rA & 7)) * 16);
    offA[i][1] = rA * 128 + (((2 * fg + 1) ^ (rA & 7)) * 16);
    offB[i][0] = rB * 128 + (((2 * fg) ^ (rB & 7)) * 16);
    offB[i][1] = rB * 128 + (((2 * fg + 1) ^ (rB & 7)) * 16);
  }

  for (int k0 = 0; k0 < 1024; k0 += 128) {
#pragma unroll
    for (int i = 0; i < 4; ++i) {
      gl_lds16(gA + (long)i * 32 * 1024, lA + i * 4096);
      gl_lds16(gB + (long)i * 32 * 1024, lB + i * 4096);
    }
    gA += 128;
    gB += 128;
    __syncthreads();

    int8v af[4], bfr[4];
#pragma unroll
    for (int i = 0; i < 4; ++i) {
      int4 lo = *(const int4*)&sA[offA[i][0]];
      int4 hi = *(const int4*)&sA[offA[i][1]];
      af[i][0] = lo.x; af[i][1] = lo.y; af[i][2] = lo.z; af[i][3] = lo.w;
      af[i][4] = hi.x; af[i][5] = hi.y; af[i][6] = hi.z; af[i][7] = hi.w;
      int4 lo2 = *(const int4*)&sB[offB[i][0]];
      int4 hi2 = *(const int4*)&sB[offB[i][1]];
      bfr[i][0] = lo2.x; bfr[i][1] = lo2.y; bfr[i][2] = lo2.z; bfr[i][3] = lo2.w;
      bfr[i][4] = hi2.x; bfr[i][5] = hi2.y; bfr[i][6] = hi2.z; bfr[i][7] = hi2.w;
    }
#pragma unroll
    for (int mi = 0; mi < 4; ++mi)
#pragma unroll
      for (int ni = 0; ni < 4; ++ni)
        acc[mi][ni] = __builtin_amdgcn_mfma_scale_f32_16x16x128_f8f6f4(
            af[mi], bfr[ni], acc[mi][ni], 0, 0, 0, 127, 0, 127);
    __syncthreads();
  }

  const int r0 = fg * 4, cc = fr;
#pragma unroll
  for (int mi = 0; mi < 4; ++mi)
#pragma unroll
    for (int ni = 0; ni < 4; ++ni)
#pragma unroll
      for (int r = 0; r < 4; ++r) {
        long gm = (long)bm * 128 + wm + mi * 16 + r0 + r;
        long gn = (long)bn * 128 + wn + ni * 16 + cc;
        P[(long)bz * 4194304L + gm * 2048 + gn] =
            f2bf(acc[mi][ni][r] * 0.03125f);
      }
}

// ---------------- softmax ----------------
__global__ __launch_bounds__(256) void softmax_k(ushort_t* __restrict__ P) {
  const long row = blockIdx.x;
  ushort_t* p = P + row * 2048;
  const int t = threadIdx.x;
  const int lane = t & 63, wave = t >> 6;
  short8 v8 = *(const short8*)&p[t * 8];
  float x[8];
#pragma unroll
  for (int j = 0; j < 8; ++j) x[j] = bf2f((ushort_t)v8[j]);
  float m = x[0];
#pragma unroll
  for (int j = 1; j < 8; ++j) m = fmaxf(m, x[j]);
  for (int off = 32; off; off >>= 1) m = fmaxf(m, __shfl_xor(m, off));
  __shared__ float rmax[4], rsum[4];
  if (lane == 0) rmax[wave] = m;
  __syncthreads();
  m = fmaxf(fmaxf(rmax[0], rmax[1]), fmaxf(rmax[2], rmax[3]));
  float s = 0.f;
#pragma unroll
  for (int j = 0; j < 8; ++j) {
    x[j] = __expf(x[j] - m);
    s += x[j];
  }
  for (int off = 32; off; off >>= 1) s += __shfl_xor(s, off);
  if (lane == 0) rsum[wave] = s;
  __syncthreads();
  s = rsum[0] + rsum[1] + rsum[2] + rsum[3];
  float inv = 1.0f / s;
  short8 o8;
#pragma unroll
  for (int j = 0; j < 8; ++j) o8[j] = (short)f2bf(x[j] * inv);
  *(short8*)&p[t * 8] = o8;
}

// ---------------- pv_gemm ----------------
// out = P x vpT^T. M=2048, N=1024, K=2048 per batch, fp32 out.
// Grid (16 bm, 8 bn, 4 bz). gl_lds staging, XOR swizzle (round-3 form).
__global__ __launch_bounds__(256, 2) void pv_gemm(
    const ushort_t* __restrict__ P, const ushort_t* __restrict__ vpT,
    float* __restrict__ out) {
  __shared__ __attribute__((aligned(16))) ushort_t sA[128 * 64];
  __shared__ __attribute__((aligned(16))) ushort_t sB[128 * 64];
  const int t = threadIdx.x, lane = t & 63, wave = t >> 6;
  const int bm = blockIdx.x, bn = blockIdx.y, bz = blockIdx.z;
  const ushort_t* Ab = P + (long)bz * 4194304L;
  const ushort_t* Bb = vpT + (long)bz * 2097152L;
  const long a_row0 = (long)bm * 128, b_row0 = (long)bn * 128;

  const int crow = t >> 3, c = t & 7, g = c ^ (crow & 7);
  const ushort_t* gA = Ab + (a_row0 + crow) * 2048L + g * 8;
  const ushort_t* gB = Bb + (b_row0 + crow) * 2048L + g * 8;
  ushort_t* lA = sA + wave * 512;
  ushort_t* lB = sB + wave * 512;

  floatx4 acc[4][4];
#pragma unroll
  for (int i = 0; i < 4; ++i)
#pragma unroll
    for (int j = 0; j < 4; ++j) acc[i][j] = {0.f, 0.f, 0.f, 0.f};

  const int wm = (wave & 1) * 64, wn = (wave >> 1) * 64;
  const int fr = lane & 15, fg = lane >> 4;
  int offA[2][4], offB[2][4];
#pragma unroll
  for (int s = 0; s < 2; ++s)
#pragma unroll
    for (int i = 0; i < 4; ++i) {
      int rowA = wm + i * 16 + fr, rowB = wn + i * 16 + fr;
      int cg = s * 4 + fg;
      offA[s][i] = rowA * 64 + ((cg ^ (rowA & 7)) * 8);
      offB[s][i] = rowB * 64 + ((cg ^ (rowB & 7)) * 8);
    }

  for (int k0 = 0; k0 < 2048; k0 += 64) {
#pragma unroll
    for (int i = 0; i < 4; ++i) {
      gl_lds16(gA + (long)i * 32 * 2048, lA + i * 2048);
      gl_lds16(gB + (long)i * 32 * 2048, lB + i * 2048);
    }
    gA += 64;
    gB += 64;
    __syncthreads();

#pragma unroll
    for (int s = 0; s < 2; ++s) {
      bf16x8 af[4], bfr[4];
#pragma unroll
      for (int i = 0; i < 4; ++i) {
        af[i] = *(const bf16x8*)&sA[offA[s][i]];
        bfr[i] = *(const bf16x8*)&sB[offB[s][i]];
      }
#pragma unroll
      for (int mi = 0; mi < 4; ++mi)
#pragma unroll
        for (int ni = 0; ni < 4; ++ni)
          acc[mi][ni] = __builtin_amdgcn_mfma_f32_16x16x32_bf16(
              af[mi], bfr[ni], acc[mi][ni], 0, 0, 0);
    }
    __syncthreads();
  }

  const int r0 = fg * 4, cc = fr;
#pragma unroll
  for (int mi = 0; mi < 4; ++mi)
#pragma unroll
    for (int ni = 0; ni < 4; ++ni) {
      long gm0 = a_row0 + wm + mi * 16 + r0;
      long gn = b_row0 + wn + ni * 16 + cc;
#pragma unroll
      for (int r = 0; r < 4; ++r)
        out[(long)bz * 2097152L + (gm0 + r) * 1024 + gn] = acc[mi][ni][r];
    }
}

// ---------------- small prep kernels ----------------
__global__ __launch_bounds__(256) void absmax_k(
    const float* __restrict__ W0, const float* __restrict__ W1,
    const float* __restrict__ W2, unsigned* __restrict__ outv) {
  const float* W = blockIdx.z == 0 ? W0 : (blockIdx.z == 1 ? W1 : W2);
  float m = 0.f;
  const long n = 1024L * 1024L;
  for (long i = (long)blockIdx.x * blockDim.x + threadIdx.x; i < n;
       i += (long)gridDim.x * blockDim.x)
    m = fmaxf(m, fabsf(W[i]));
  for (int off = 32; off; off >>= 1) m = fmaxf(m, __shfl_xor(m, off));
  __shared__ float red[4];
  int lane = threadIdx.x & 63, wave = threadIdx.x >> 6;
  if (lane == 0) red[wave] = m;
  __syncthreads();
  if (threadIdx.x == 0) {
    m = fmaxf(fmaxf(red[0], red[1]), fmaxf(red[2], red[3]));
    atomicMax(&outv[blockIdx.z], __float_as_uint(m));  // positive: uint order
  }
}

__global__ __launch_bounds__(256) void quant_w_k(
    const float* __restrict__ W0, const float* __restrict__ W1,
    const float* __restrict__ W2, const unsigned* __restrict__ scales,
    ushort_t* __restrict__ Wt) {
  const int z = blockIdx.z;
  const float* W = z == 0 ? W0 : (z == 1 ? W1 : W2);
  const float s = __uint_as_float(scales[z]) * (1.0f / 128.0f);
  __shared__ float tile[32][33];
  const int tx = threadIdx.x & 31, ty = threadIdx.x >> 5;
  const int k0 = blockIdx.y * 32, n0 = blockIdx.x * 32;
#pragma unroll
  for (int i = 0; i < 4; ++i)
    tile[ty + i * 8][tx] = W[(long)(k0 + ty + i * 8) * 1024 + n0 + tx];
  __syncthreads();
  ushort_t* wt = Wt + (long)z * 1024 * 1024;
#pragma unroll
  for (int i = 0; i < 4; ++i) {
    float w = tile[tx][ty + i * 8];
    float qv = rintf(w / s) * s;  // rintf = RNE = jnp.round
    wt[(long)(n0 + ty + i * 8) * 1024 + k0 + tx] = f2bf(qv);
  }
}

extern "C" void kernel_launch(void* const* d_in, const int* in_sizes, int n_in,
                              void* d_out, int out_size, void* d_ws,
                              size_t ws_size, hipStream_t stream) {
  const float* q = (const float*)d_in[0];
  const float* k = (const float*)d_in[1];
  const float* v = (const float*)d_in[2];
  const float* Wq = (const float*)d_in[3];
  const float* bq = (const float*)d_in[4];
  const float* Wk = (const float*)d_in[5];
  const float* bk = (const float*)d_in[6];
  const float* Wv = (const float*)d_in[7];
  const float* bv = (const float*)d_in[8];
  float* out = (float*)d_out;
  char* ws = (char*)d_ws;

  // Workspace layout (bytes), total 106,955,008 (known-good size):
  //   scales @0 (256)
  //   Wt     @256 (6 MB)
  //   qp8 @6,291,712  (8 MB)
  //   kp8 @14,680,320 (8 MB)
  //   vpT @23,068,928 (16 MB)  [4][1024][2048] bf16
  //   P   @39,846,144 (64 MB)  [4][2048][2048] bf16
  unsigned* scales = (unsigned*)ws;
  ushort_t* Wt = (ushort_t*)(ws + 256);
  unsigned char* qp8 = (unsigned char*)(ws + 6291712);
  unsigned char* kp8 = (unsigned char*)(ws + 14680320);
  ushort_t* vpT = (ushort_t*)(ws + 23068928);
  ushort_t* P = (ushort_t*)(ws + 39846144);

  hipMemsetAsync(scales, 0, 64, stream);
  absmax_k<<<dim3(64, 1, 3), 256, 0, stream>>>(Wq, Wk, Wv, scales);
  quant_w_k<<<dim3(32, 32, 3), 256, 0, stream>>>(Wq, Wk, Wv, scales, Wt);

  proj_gemm<<<dim3(64, 8, 3), 256, 0, stream>>>(q, k, v, Wt, qp8, kp8, vpT, bq,
                                                bk, bv);
  qk_fp8<<<dim3(16, 16, 4), 256, 0, stream>>>(qp8, kp8, P);
  softmax_k<<<8192, 256, 0, stream>>>(P);
  pv_gemm<<<dim3(16, 8, 4), 256, 0, stream>>>(P, vpT, out);
}